// Round 1
// 1114.767 us; speedup vs baseline: 1.1098x; 1.1098x over previous
//
#include <hip/hip_runtime.h>

// ---------------- problem constants ----------------
#define WORDS    528384          // 2048 * 258 words = 16,908,288 bits >= 169*100000 hash bins
#define NB_SCAN  258

// ws layout (u32 units) — unchanged from previous version
#define IDX_SCALARS 0                       // [0]=xmax, [1]=n_unique
#define IDX_MASK1   16
#define IDX_MASK2   (16 + WORDS)
#define IDX_COUNTS  (16 + 2*WORDS)          // N u32: singleton -> user idx, multi -> member count
#define IDX_WBASE(nrows)  (16 + 2*WORDS + (nrows))
#define IDX_PART(nrows)   (IDX_WBASE(nrows) + WORDS)
#define IDX_PART2(nrows)  (IDX_PART(nrows) + 512)
#define IDX_HRANK(nrows)  (IDX_PART2(nrows) + 512)

typedef __attribute__((ext_vector_type(8))) short s8x;   // 8 bf16 in 4 VGPRs (MFMA A/B frag)
typedef __attribute__((ext_vector_type(4))) float f4x;   // MFMA C/D frag

__device__ __forceinline__ float tanh_fast(float z) {
    float e = __expf(2.0f * z);
    return 1.0f - 2.0f * __builtin_amdgcn_rcpf(e + 1.0f);
}

// fp32 -> bf16 bits, round-to-nearest-even
__device__ __forceinline__ unsigned bfr(float f) {
    unsigned u = __float_as_uint(f);
    return (u + 0x7FFFu + ((u >> 16) & 1u)) >> 16;
}

// split 8 floats into bf16 hi + bf16 lo (a ~= hi + lo, residual ~2^-18 rel)
__device__ __forceinline__ void split8(const float* fv, s8x& hi, s8x& lo) {
    #pragma unroll
    for (int e = 0; e < 8; ++e) {
        unsigned hb = bfr(fv[e]);
        hi[e] = (short)hb;
        lo[e] = (short)bfr(fv[e] - __uint_as_float(hb << 16));
    }
}

// ---- 1) xmax reduction only (no more 128 MB zero-fill of out) ----
__global__ void k_init(const int* __restrict__ x, unsigned* __restrict__ scalars, int n) {
    int g = blockIdx.x * blockDim.x + threadIdx.x;
    int row = g < n ? g : n - 1;
    unsigned v = (unsigned)x[row];
    #pragma unroll
    for (int off = 32; off > 0; off >>= 1) {
        unsigned o = (unsigned)__shfl_xor((int)v, off);
        v = v > o ? v : o;
    }
    if ((threadIdx.x & 63) == 0) atomicMax(scalars, v);
}

// ---- 2) set presence bit; second mask marks multi-member groups ----
__global__ void k_bits(const int* __restrict__ x, const int* __restrict__ t,
                       const unsigned* __restrict__ scalars,
                       unsigned* __restrict__ mask1, unsigned* __restrict__ mask2, int n) {
    int g = blockIdx.x * blockDim.x + threadIdx.x;
    if (g >= n) return;
    unsigned d = scalars[0] + 1u;
    unsigned h = (unsigned)t[g] * d + (unsigned)x[g];
    unsigned w = h >> 5, bit = 1u << (h & 31);
    unsigned old = atomicOr(&mask1[w], bit);
    if (old & bit) atomicOr(&mask2[w], bit);
}

// ---- 3) prefix-popcount scan over the bitmask (3 kernels) ----
__global__ void k_scan1(const unsigned* __restrict__ mask1, unsigned* __restrict__ part) {
    const int t = threadIdx.x, b = blockIdx.x;
    const unsigned* wp = mask1 + (size_t)b * 2048 + t * 8;
    unsigned s = 0;
    #pragma unroll
    for (int i = 0; i < 8; ++i) s += __popc(wp[i]);
    #pragma unroll
    for (int off = 32; off > 0; off >>= 1) s += (unsigned)__shfl_xor((int)s, off);
    __shared__ unsigned red[4];
    if ((t & 63) == 0) red[t >> 6] = s;
    __syncthreads();
    if (t == 0) part[b] = red[0] + red[1] + red[2] + red[3];
}

__global__ void k_scan2(const unsigned* __restrict__ part, unsigned* __restrict__ part2,
                        unsigned* __restrict__ scalars) {
    const int t = threadIdx.x;
    __shared__ unsigned sm[512];
    unsigned v = (t < NB_SCAN) ? part[t] : 0u;
    sm[t] = v;
    __syncthreads();
    for (int off = 1; off < 512; off <<= 1) {
        unsigned add = (t >= off) ? sm[t - off] : 0u;
        __syncthreads();
        sm[t] += add;
        __syncthreads();
    }
    part2[t] = sm[t] - v;                 // exclusive block offsets
    if (t == 511) scalars[1] = sm[511];   // n_unique
}

__global__ void k_scan3(const unsigned* __restrict__ mask1, const unsigned* __restrict__ part2,
                        unsigned* __restrict__ wbase) {
    const int t = threadIdx.x, b = blockIdx.x;
    const int lane = t & 63, wid = t >> 6;
    const size_t w0 = (size_t)b * 2048 + t * 8;
    unsigned pc[8], tsum = 0;
    #pragma unroll
    for (int i = 0; i < 8; ++i) { pc[i] = __popc(mask1[w0 + i]); tsum += pc[i]; }
    unsigned incl = tsum;
    #pragma unroll
    for (int off = 1; off < 64; off <<= 1) {
        unsigned vv = (unsigned)__shfl_up((int)incl, off);
        if (lane >= off) incl += vv;
    }
    __shared__ unsigned wt[4];
    if (lane == 63) wt[wid] = incl;
    __syncthreads();
    unsigned base = part2[b] + (incl - tsum);
    for (int i = 0; i < wid; ++i) base += wt[i];
    #pragma unroll
    for (int i = 0; i < 8; ++i) { wbase[w0 + i] = base; base += pc[i]; }
}

// ---- 3b) zero u_sum staging ONLY for multi-member ranks (~30K rows, ~4 MB) ----
__global__ void k_zero_multi(const unsigned* __restrict__ mask1, const unsigned* __restrict__ mask2,
                             const unsigned* __restrict__ wbase, float* __restrict__ out) {
    int w = blockIdx.x * blockDim.x + threadIdx.x;
    if (w >= WORDS) return;
    unsigned m2 = mask2[w];
    if (!m2) return;
    unsigned m1 = mask1[w];
    unsigned base = wbase[w];
    float4 z = make_float4(0.f, 0.f, 0.f, 0.f);
    do {
        int b = __builtin_ctz(m2);
        m2 &= m2 - 1u;
        unsigned r = base + __popc(m1 & ((1u << b) - 1u));
        float4* dst = (float4*)(out + (size_t)r * 128 + 96);
        #pragma unroll
        for (int q = 0; q < 8; ++q) dst[q] = z;
    } while (m2);
}

// ---- 4) slim scatter: singleton ranks store just the user index; multi ranks
//         atomic-add user embeddings into out[:,96:128] staging. Pack (x,t,multi)
//         into hrank so the GEMM needs no integer division. ----
__global__ void k_scatter(const int* __restrict__ x, const int* __restrict__ t,
                          const int* __restrict__ u, const float* __restrict__ user_emb,
                          const unsigned* __restrict__ scalars,
                          const unsigned* __restrict__ mask1, const unsigned* __restrict__ mask2,
                          const unsigned* __restrict__ wbase,
                          unsigned* __restrict__ counts, unsigned* __restrict__ hrank,
                          float* __restrict__ out, int n) {
    int j = blockIdx.x * blockDim.x + threadIdx.x;
    if (j >= n) return;
    unsigned d  = scalars[0] + 1u;
    unsigned xv = (unsigned)x[j], tv = (unsigned)t[j];
    unsigned h = tv * d + xv;
    unsigned w = h >> 5, bp = h & 31;
    unsigned r = wbase[w] + __popc(mask1[w] & ((1u << bp) - 1u));
    unsigned multi = (mask2[w] >> bp) & 1u;
    unsigned pack = xv | (tv << 17) | (multi << 31);   // x<2^17, t<2^8
    hrank[r] = pack;                                   // multi: same value from all members, benign
    if (!multi) {
        counts[r] = (unsigned)u[j];                    // reuse counts[] as user-index for singletons
    } else {
        atomicAdd(&counts[r], 1u);
        const float4* ue = (const float4*)(user_emb + (size_t)u[j] * 32);
        float* dst = out + (size_t)r * 128 + 96;
        #pragma unroll
        for (int q = 0; q < 8; ++q) {
            float4 v = ue[q];
            unsafeAtomicAdd(dst + q * 4 + 0, v.x);
            unsafeAtomicAdd(dst + q * 4 + 1, v.y);
            unsafeAtomicAdd(dst + q * 4 + 2, v.z);
            unsafeAtomicAdd(dst + q * 4 + 3, v.w);
        }
    }
}

// ---- 5) MFMA GEMM: gather A direct-to-registers, W fully register-resident.
//         bf16x2 split: C += Ahi*Whi + Alo*Whi + Ahi*Wlo  (near-fp32 accuracy).
//         Per block: 4 waves, 64 rows x 128 cols per stripe; wave = 32 rows x 64 cols.
//         mfma_f32_16x16x32_bf16 lane map: A[l&15][8*(l>>4)+j], B[8*(l>>4)+j][l&15],
//         D row=4*(l>>4)+reg, col=l&15. ----
__global__ __launch_bounds__(256, 2) void k_gemm(
    const float* __restrict__ loc_emb, const float* __restrict__ time_emb,
    const float* __restrict__ user_emb,
    const float* __restrict__ W, const float* __restrict__ bias,
    const unsigned* __restrict__ scalars, const unsigned* __restrict__ counts,
    const unsigned* __restrict__ hrank, float* __restrict__ out, int n) {
    const int tid  = threadIdx.x;
    const int wave = tid >> 6, lane = tid & 63;
    const int lr = lane & 15, lg = lane >> 4;
    const int wrow = wave & 1, wcol = wave >> 1;
    const int cbase = wcol * 64;
    const unsigned nu = scalars[1];

    // ---- W fragments (hi+lo), register-resident for this wave's 64 cols ----
    s8x bhi[4][4], blo[4][4];   // [col-tile][k-step]
    {
        const float* wr = W + (size_t)(cbase + lr) * 128 + lg * 8;
        #pragma unroll
        for (int ct = 0; ct < 4; ++ct) {
            #pragma unroll
            for (int ks = 0; ks < 4; ++ks) {
                const float4* p = (const float4*)(wr + ct * 16 * 128 + ks * 32);
                float4 v0 = p[0], v1 = p[1];
                float fv[8] = {v0.x, v0.y, v0.z, v0.w, v1.x, v1.y, v1.z, v1.w};
                split8(fv, bhi[ct][ks], blo[ct][ks]);
            }
        }
    }
    float bv[4];
    #pragma unroll
    for (int ct = 0; ct < 4; ++ct) bv[ct] = bias[cbase + ct * 16 + lr];

    const int nstripes = (n + 63) >> 6;
    for (int stripe = blockIdx.x; stripe < nstripes; stripe += gridDim.x) {
        const int r0 = stripe * 64;
        if ((unsigned)r0 >= nu) {                 // whole stripe past n_unique: zeros
            int rows = (n - r0 < 64) ? (n - r0) : 64;
            float4 z = make_float4(0.f, 0.f, 0.f, 0.f);
            float4* o4 = (float4*)(out + (size_t)r0 * 128);
            for (int i = tid; i < rows * 32; i += 256) o4[i] = z;
            continue;                             // block-uniform branch, safe vs barrier
        }
        const int rb = r0 + wrow * 32;

        // ---- per-row meta (16 rows per tile, 4-lane redundancy) ----
        unsigned xx[2], tt[2], cnt[2], mlt[2];
        bool val[2];
        #pragma unroll
        for (int rt = 0; rt < 2; ++rt) {
            unsigned r = (unsigned)(rb + rt * 16 + lr);
            val[rt] = r < nu;
            unsigned hv = val[rt] ? hrank[r] : 0u;
            xx[rt]  = hv & 0x1FFFFu;
            tt[rt]  = (hv >> 17) & 0xFFu;
            mlt[rt] = hv >> 31;
            cnt[rt] = val[rt] ? counts[r] : 0u;
        }

        f4x acc[2][4];
        {
            f4x z = {0.f, 0.f, 0.f, 0.f};
            #pragma unroll
            for (int rt = 0; rt < 2; ++rt)
                #pragma unroll
                for (int ct = 0; ct < 4; ++ct) acc[rt][ct] = z;
        }

        #pragma unroll
        for (int ks = 0; ks < 4; ++ks) {
            s8x ahi[2], alo[2];
            #pragma unroll
            for (int rt = 0; rt < 2; ++rt) {
                if (val[rt]) {
                    const float4* p;
                    float sc = 1.0f;
                    if (ks == 0)      p = (const float4*)(loc_emb  + (size_t)xx[rt] * 64 + lg * 8);
                    else if (ks == 1) p = (const float4*)(loc_emb  + (size_t)xx[rt] * 64 + 32 + lg * 8);
                    else if (ks == 2) p = (const float4*)(time_emb + (size_t)tt[rt] * 32 + lg * 8);
                    else {
                        if (mlt[rt]) {
                            p  = (const float4*)(out + (size_t)(rb + rt * 16 + lr) * 128 + 96 + lg * 8);
                            sc = __builtin_amdgcn_rcpf((float)cnt[rt]);
                        } else {
                            p  = (const float4*)(user_emb + (size_t)cnt[rt] * 32 + lg * 8);
                        }
                    }
                    float4 v0 = p[0], v1 = p[1];
                    float fv[8] = {v0.x * sc, v0.y * sc, v0.z * sc, v0.w * sc,
                                   v1.x * sc, v1.y * sc, v1.z * sc, v1.w * sc};
                    split8(fv, ahi[rt], alo[rt]);
                } else {
                    s8x z = {0, 0, 0, 0, 0, 0, 0, 0};
                    ahi[rt] = z; alo[rt] = z;
                }
            }
            #pragma unroll
            for (int ct = 0; ct < 4; ++ct) {
                #pragma unroll
                for (int rt = 0; rt < 2; ++rt) {
                    f4x c = acc[rt][ct];
                    c = __builtin_amdgcn_mfma_f32_16x16x32_bf16(ahi[rt], bhi[ct][ks], c, 0, 0, 0);
                    c = __builtin_amdgcn_mfma_f32_16x16x32_bf16(alo[rt], bhi[ct][ks], c, 0, 0, 0);
                    c = __builtin_amdgcn_mfma_f32_16x16x32_bf16(ahi[rt], blo[ct][ks], c, 0, 0, 0);
                    acc[rt][ct] = c;
                }
            }
        }

        // all staging reads (cols 96..127) must complete before any wave overwrites them
        __syncthreads();

        #pragma unroll
        for (int rt = 0; rt < 2; ++rt) {
            #pragma unroll
            for (int ct = 0; ct < 4; ++ct) {
                const int c = cbase + ct * 16 + lr;
                #pragma unroll
                for (int p = 0; p < 4; ++p) {
                    int rr = rb + rt * 16 + lg * 4 + p;
                    float o = 0.f;
                    if ((unsigned)rr < nu) o = tanh_fast(acc[rt][ct][p] + bv[ct]);
                    if (rr < n) out[(size_t)rr * 128 + c] = o;
                }
            }
        }
    }
}

extern "C" void kernel_launch(void* const* d_in, const int* in_sizes, int n_in,
                              void* d_out, int out_size, void* d_ws, size_t ws_size,
                              hipStream_t stream) {
    const float* loc_emb  = (const float*)d_in[0];
    const float* time_emb = (const float*)d_in[1];
    const float* user_emb = (const float*)d_in[2];
    const float* W        = (const float*)d_in[3];
    const float* bias     = (const float*)d_in[4];
    const int*   x        = (const int*)d_in[5];
    const int*   t        = (const int*)d_in[6];
    const int*   u        = (const int*)d_in[7];
    float* out = (float*)d_out;
    const int n = in_sizes[5];   // 1,000,000

    unsigned* ws32    = (unsigned*)d_ws;
    unsigned* scalars = ws32 + IDX_SCALARS;
    unsigned* mask1   = ws32 + IDX_MASK1;
    unsigned* mask2   = ws32 + IDX_MASK2;
    unsigned* counts  = ws32 + IDX_COUNTS;
    unsigned* wbase   = ws32 + IDX_WBASE(n);
    unsigned* part    = ws32 + IDX_PART(n);
    unsigned* part2   = ws32 + IDX_PART2(n);
    unsigned* hrank   = ws32 + IDX_HRANK(n);

    const size_t zero_bytes = (size_t)(16 + 2 * WORDS + n) * 4;  // scalars+masks+counts
    hipMemsetAsync(d_ws, 0, zero_bytes, stream);

    int nb = (n + 255) / 256;
    k_init      <<<nb, 256, 0, stream>>>(x, scalars, n);
    k_bits      <<<nb, 256, 0, stream>>>(x, t, scalars, mask1, mask2, n);
    k_scan1     <<<NB_SCAN, 256, 0, stream>>>(mask1, part);
    k_scan2     <<<1, 512, 0, stream>>>(part, part2, scalars);
    k_scan3     <<<NB_SCAN, 256, 0, stream>>>(mask1, part2, wbase);
    k_zero_multi<<<(WORDS + 255) / 256, 256, 0, stream>>>(mask1, mask2, wbase, out);
    k_scatter   <<<nb, 256, 0, stream>>>(x, t, u, user_emb, scalars, mask1, mask2,
                                         wbase, counts, hrank, out, n);
    // 15625 stripes = 5^6 -> 3125 blocks x exactly 5 stripes, perfectly balanced
    k_gemm      <<<3125, 256, 0, stream>>>(loc_emb, time_emb, user_emb, W, bias,
                                           scalars, counts, hrank, out, n);
}

// Round 2
// 1052.956 us; speedup vs baseline: 1.1750x; 1.0587x over previous
//
#include <hip/hip_runtime.h>
#include <hip/hip_bf16.h>

// ---------------- problem constants ----------------
#define WORDS    528384          // 2048 * 258 words = 16,908,288 bits >= 169*100000 hash bins
#define NB_SCAN  258

// ws layout (u32 units) — unchanged
#define IDX_SCALARS 0                       // [0]=xmax, [1]=n_unique
#define IDX_MASK1   16
#define IDX_MASK2   (16 + WORDS)
#define IDX_COUNTS  (16 + 2*WORDS)          // N u32: singleton -> user idx, multi -> member count
#define IDX_WBASE(nrows)  (16 + 2*WORDS + (nrows))
#define IDX_PART(nrows)   (IDX_WBASE(nrows) + WORDS)
#define IDX_PART2(nrows)  (IDX_PART(nrows) + 512)
#define IDX_HRANK(nrows)  (IDX_PART2(nrows) + 512)

typedef __attribute__((ext_vector_type(8))) short s8x;   // 8 bf16 in 4 VGPRs (MFMA A/B frag)
typedef __attribute__((ext_vector_type(4))) float f4x;   // MFMA C/D frag

__device__ __forceinline__ float tanh_fast(float z) {
    float e = __expf(2.0f * z);
    return 1.0f - 2.0f * __builtin_amdgcn_rcpf(e + 1.0f);
}

// tanh via odd deg-5 Taylor; |z| <= 0.25 -> err < 3.3e-6. Guarded fallback for tails.
__device__ __forceinline__ float tanh_poly(float z) {
    float t = z * z;
    float w = __builtin_fmaf(t, 0.13333333f, -0.33333333f);   // c5*t + c3
    float r = z * __builtin_fmaf(t, w, 1.0f);                 // z*(1 + t*(c3 + c5 t))
    if (__builtin_expect(__builtin_fabsf(z) > 0.25f, 0)) r = tanh_fast(z);
    return r;
}

// fp32 -> bf16 (RNE) via the HIP intrinsic; compiler emits v_cvt_pk_bf16_f32 pairs.
__device__ __forceinline__ short f2bf(float f) {
    __hip_bfloat16 h = __float2bfloat16(f);
    short s;
    __builtin_memcpy(&s, &h, 2);
    return s;
}

__device__ __forceinline__ s8x pack8(float4 a, float4 b) {
    s8x r;
    r[0] = f2bf(a.x); r[1] = f2bf(a.y); r[2] = f2bf(a.z); r[3] = f2bf(a.w);
    r[4] = f2bf(b.x); r[5] = f2bf(b.y); r[6] = f2bf(b.z); r[7] = f2bf(b.w);
    return r;
}

// ---- 1) xmax reduction ----
__global__ void k_init(const int* __restrict__ x, unsigned* __restrict__ scalars, int n) {
    int g = blockIdx.x * blockDim.x + threadIdx.x;
    int row = g < n ? g : n - 1;
    unsigned v = (unsigned)x[row];
    #pragma unroll
    for (int off = 32; off > 0; off >>= 1) {
        unsigned o = (unsigned)__shfl_xor((int)v, off);
        v = v > o ? v : o;
    }
    if ((threadIdx.x & 63) == 0) atomicMax(scalars, v);
}

// ---- 2) set presence bit; second mask marks multi-member groups ----
__global__ void k_bits(const int* __restrict__ x, const int* __restrict__ t,
                       const unsigned* __restrict__ scalars,
                       unsigned* __restrict__ mask1, unsigned* __restrict__ mask2, int n) {
    int g = blockIdx.x * blockDim.x + threadIdx.x;
    if (g >= n) return;
    unsigned d = scalars[0] + 1u;
    unsigned h = (unsigned)t[g] * d + (unsigned)x[g];
    unsigned w = h >> 5, bit = 1u << (h & 31);
    unsigned old = atomicOr(&mask1[w], bit);
    if (old & bit) atomicOr(&mask2[w], bit);
}

// ---- 3) prefix-popcount scan over the bitmask (3 kernels) ----
__global__ void k_scan1(const unsigned* __restrict__ mask1, unsigned* __restrict__ part) {
    const int t = threadIdx.x, b = blockIdx.x;
    const unsigned* wp = mask1 + (size_t)b * 2048 + t * 8;
    unsigned s = 0;
    #pragma unroll
    for (int i = 0; i < 8; ++i) s += __popc(wp[i]);
    #pragma unroll
    for (int off = 32; off > 0; off >>= 1) s += (unsigned)__shfl_xor((int)s, off);
    __shared__ unsigned red[4];
    if ((t & 63) == 0) red[t >> 6] = s;
    __syncthreads();
    if (t == 0) part[b] = red[0] + red[1] + red[2] + red[3];
}

__global__ void k_scan2(const unsigned* __restrict__ part, unsigned* __restrict__ part2,
                        unsigned* __restrict__ scalars) {
    const int t = threadIdx.x;
    __shared__ unsigned sm[512];
    unsigned v = (t < NB_SCAN) ? part[t] : 0u;
    sm[t] = v;
    __syncthreads();
    for (int off = 1; off < 512; off <<= 1) {
        unsigned add = (t >= off) ? sm[t - off] : 0u;
        __syncthreads();
        sm[t] += add;
        __syncthreads();
    }
    part2[t] = sm[t] - v;                 // exclusive block offsets
    if (t == 511) scalars[1] = sm[511];   // n_unique
}

__global__ void k_scan3(const unsigned* __restrict__ mask1, const unsigned* __restrict__ part2,
                        unsigned* __restrict__ wbase) {
    const int t = threadIdx.x, b = blockIdx.x;
    const int lane = t & 63, wid = t >> 6;
    const size_t w0 = (size_t)b * 2048 + t * 8;
    unsigned pc[8], tsum = 0;
    #pragma unroll
    for (int i = 0; i < 8; ++i) { pc[i] = __popc(mask1[w0 + i]); tsum += pc[i]; }
    unsigned incl = tsum;
    #pragma unroll
    for (int off = 1; off < 64; off <<= 1) {
        unsigned vv = (unsigned)__shfl_up((int)incl, off);
        if (lane >= off) incl += vv;
    }
    __shared__ unsigned wt[4];
    if (lane == 63) wt[wid] = incl;
    __syncthreads();
    unsigned base = part2[b] + (incl - tsum);
    for (int i = 0; i < wid; ++i) base += wt[i];
    #pragma unroll
    for (int i = 0; i < 8; ++i) { wbase[w0 + i] = base; base += pc[i]; }
}

// ---- 3b) zero u_sum staging ONLY for multi-member ranks (~30K rows) ----
__global__ void k_zero_multi(const unsigned* __restrict__ mask1, const unsigned* __restrict__ mask2,
                             const unsigned* __restrict__ wbase, float* __restrict__ out) {
    int w = blockIdx.x * blockDim.x + threadIdx.x;
    if (w >= WORDS) return;
    unsigned m2 = mask2[w];
    if (!m2) return;
    unsigned m1 = mask1[w];
    unsigned base = wbase[w];
    float4 z = make_float4(0.f, 0.f, 0.f, 0.f);
    do {
        int b = __builtin_ctz(m2);
        m2 &= m2 - 1u;
        unsigned r = base + __popc(m1 & ((1u << b) - 1u));
        float4* dst = (float4*)(out + (size_t)r * 128 + 96);
        #pragma unroll
        for (int q = 0; q < 8; ++q) dst[q] = z;
    } while (m2);
}

// ---- 4) slim scatter: singleton ranks store just the user index; multi ranks
//         atomic-add user embeddings into out[:,96:128] staging. ----
__global__ void k_scatter(const int* __restrict__ x, const int* __restrict__ t,
                          const int* __restrict__ u, const float* __restrict__ user_emb,
                          const unsigned* __restrict__ scalars,
                          const unsigned* __restrict__ mask1, const unsigned* __restrict__ mask2,
                          const unsigned* __restrict__ wbase,
                          unsigned* __restrict__ counts, unsigned* __restrict__ hrank,
                          float* __restrict__ out, int n) {
    int j = blockIdx.x * blockDim.x + threadIdx.x;
    if (j >= n) return;
    unsigned d  = scalars[0] + 1u;
    unsigned xv = (unsigned)x[j], tv = (unsigned)t[j];
    unsigned h = tv * d + xv;
    unsigned w = h >> 5, bp = h & 31;
    unsigned r = wbase[w] + __popc(mask1[w] & ((1u << bp) - 1u));
    unsigned multi = (mask2[w] >> bp) & 1u;
    unsigned pack = xv | (tv << 17) | (multi << 31);   // x<2^17, t<2^8
    hrank[r] = pack;                                   // multi: same value from all members, benign
    if (!multi) {
        counts[r] = (unsigned)u[j];                    // reuse counts[] as user-index for singletons
    } else {
        atomicAdd(&counts[r], 1u);
        const float4* ue = (const float4*)(user_emb + (size_t)u[j] * 32);
        float* dst = out + (size_t)r * 128 + 96;
        #pragma unroll
        for (int q = 0; q < 8; ++q) {
            float4 v = ue[q];
            unsafeAtomicAdd(dst + q * 4 + 0, v.x);
            unsafeAtomicAdd(dst + q * 4 + 1, v.y);
            unsafeAtomicAdd(dst + q * 4 + 2, v.z);
            unsafeAtomicAdd(dst + q * 4 + 3, v.w);
        }
    }
}

// ---- 5) MFMA GEMM, swapped-operand form.
//      mfma(Wfrag, Afrag): D[m][n] with m = W-column (16 of them), n = output row.
//      => lane (lr,lg) holds, per (rt,ct), rows rb+rt*16+lr, cols cbase+ct*16+lg*4..+3
//      => epilogue is 8 float4 stores per thread, per-lane-uniform row validity.
//      A-side: single bf16 (RNE); W-side: single bf16 — dot-error ~1e-4 max, well
//      under the 4.88e-4 absmax already saturated by non-GEMM effects.
__global__ __launch_bounds__(256, 3) void k_gemm(
    const float* __restrict__ loc_emb, const float* __restrict__ time_emb,
    const float* __restrict__ user_emb,
    const float* __restrict__ W, const float* __restrict__ bias,
    const unsigned* __restrict__ scalars, const unsigned* __restrict__ counts,
    const unsigned* __restrict__ hrank, float* __restrict__ out, int n) {
    const int tid  = threadIdx.x;
    const int wave = tid >> 6, lane = tid & 63;
    const int lr = lane & 15, lg = lane >> 4;
    const int wrow = wave & 1, wcol = wave >> 1;
    const int cbase = wcol * 64;
    const unsigned nu = scalars[1];

    // ---- W fragments (single bf16), register-resident: 16 x s8x = 64 VGPR ----
    s8x wf[4][4];   // [col-tile][k-step]; lane holds W[cbase+lr][k = ks*32 + lg*8 .. +8]
    {
        const float* wr = W + (size_t)(cbase + lr) * 128 + lg * 8;
        #pragma unroll
        for (int ct = 0; ct < 4; ++ct) {
            #pragma unroll
            for (int ks = 0; ks < 4; ++ks) {
                const float4* p = (const float4*)(wr + ct * 16 * 128 + ks * 32);
                wf[ct][ks] = pack8(p[0], p[1]);
            }
        }
    }
    float4 bias4[4];
    #pragma unroll
    for (int ct = 0; ct < 4; ++ct)
        bias4[ct] = ((const float4*)bias)[(cbase >> 2) + ct * 4 + lg];

    const int nstripes = (n + 63) >> 6;
    for (int stripe = blockIdx.x; stripe < nstripes; stripe += gridDim.x) {
        const int r0 = stripe * 64;
        if ((unsigned)r0 >= nu) {                 // whole stripe past n_unique: zeros
            int rows = (n - r0 < 64) ? (n - r0) : 64;
            float4 z = make_float4(0.f, 0.f, 0.f, 0.f);
            float4* o4 = (float4*)(out + (size_t)r0 * 128);
            for (int i = tid; i < rows * 32; i += 256) o4[i] = z;
            continue;                             // block-uniform branch, safe vs barrier
        }
        const int rb = r0 + wrow * 32;

        // ---- per-row meta: precompute gather pointers (16 rows/tile, lg-redundant) ----
        const float* pl[2]; const float* pt[2]; const float* pu[2];
        float sc[2]; bool val[2];
        #pragma unroll
        for (int rt = 0; rt < 2; ++rt) {
            int rr = rb + rt * 16 + lr;
            val[rt] = (unsigned)rr < nu;
            unsigned hv = val[rt] ? hrank[rr] : 0u;
            unsigned cv = val[rt] ? counts[rr] : 0u;
            unsigned xx = hv & 0x1FFFFu, tv = (hv >> 17) & 0xFFu;
            pl[rt] = loc_emb  + (size_t)xx * 64 + lg * 8;
            pt[rt] = time_emb + (size_t)tv * 32 + lg * 8;
            if (hv >> 31) {
                pu[rt] = out + (size_t)rr * 128 + 96 + lg * 8;
                sc[rt] = __builtin_amdgcn_rcpf((float)cv);
            } else {
                pu[rt] = user_emb + (size_t)cv * 32 + lg * 8;
                sc[rt] = 1.0f;
            }
        }

        f4x acc[2][4];
        {
            f4x z = {0.f, 0.f, 0.f, 0.f};
            #pragma unroll
            for (int rt = 0; rt < 2; ++rt)
                #pragma unroll
                for (int ct = 0; ct < 4; ++ct) acc[rt][ct] = z;
        }

        #pragma unroll
        for (int ks = 0; ks < 4; ++ks) {
            s8x av[2];
            #pragma unroll
            for (int rt = 0; rt < 2; ++rt) {
                if (val[rt]) {
                    const float4* p;
                    if (ks == 0)      p = (const float4*)(pl[rt]);
                    else if (ks == 1) p = (const float4*)(pl[rt] + 32);
                    else if (ks == 2) p = (const float4*)(pt[rt]);
                    else              p = (const float4*)(pu[rt]);
                    float4 v0 = p[0], v1 = p[1];
                    if (ks == 3) {
                        float s = sc[rt];
                        v0.x *= s; v0.y *= s; v0.z *= s; v0.w *= s;
                        v1.x *= s; v1.y *= s; v1.z *= s; v1.w *= s;
                    }
                    av[rt] = pack8(v0, v1);
                } else {
                    s8x z = {0, 0, 0, 0, 0, 0, 0, 0};
                    av[rt] = z;
                }
            }
            #pragma unroll
            for (int ct = 0; ct < 4; ++ct)
                #pragma unroll
                for (int rt = 0; rt < 2; ++rt)
                    acc[rt][ct] = __builtin_amdgcn_mfma_f32_16x16x32_bf16(
                        wf[ct][ks], av[rt], acc[rt][ct], 0, 0, 0);
        }

        // all staging reads (cols 96..127) must complete before wcol=1 waves overwrite them
        __syncthreads();

        #pragma unroll
        for (int rt = 0; rt < 2; ++rt) {
            int rr = rb + rt * 16 + lr;
            float* orow = out + (size_t)rr * 128 + cbase + lg * 4;
            #pragma unroll
            for (int ct = 0; ct < 4; ++ct) {
                float4 o;
                if (val[rt]) {
                    o.x = tanh_poly(acc[rt][ct][0] + bias4[ct].x);
                    o.y = tanh_poly(acc[rt][ct][1] + bias4[ct].y);
                    o.z = tanh_poly(acc[rt][ct][2] + bias4[ct].z);
                    o.w = tanh_poly(acc[rt][ct][3] + bias4[ct].w);
                } else {
                    o = make_float4(0.f, 0.f, 0.f, 0.f);
                }
                *(float4*)(orow + ct * 16) = o;
            }
        }
    }
}

extern "C" void kernel_launch(void* const* d_in, const int* in_sizes, int n_in,
                              void* d_out, int out_size, void* d_ws, size_t ws_size,
                              hipStream_t stream) {
    const float* loc_emb  = (const float*)d_in[0];
    const float* time_emb = (const float*)d_in[1];
    const float* user_emb = (const float*)d_in[2];
    const float* W        = (const float*)d_in[3];
    const float* bias     = (const float*)d_in[4];
    const int*   x        = (const int*)d_in[5];
    const int*   t        = (const int*)d_in[6];
    const int*   u        = (const int*)d_in[7];
    float* out = (float*)d_out;
    const int n = in_sizes[5];   // 1,000,000

    unsigned* ws32    = (unsigned*)d_ws;
    unsigned* scalars = ws32 + IDX_SCALARS;
    unsigned* mask1   = ws32 + IDX_MASK1;
    unsigned* mask2   = ws32 + IDX_MASK2;
    unsigned* counts  = ws32 + IDX_COUNTS;
    unsigned* wbase   = ws32 + IDX_WBASE(n);
    unsigned* part    = ws32 + IDX_PART(n);
    unsigned* part2   = ws32 + IDX_PART2(n);
    unsigned* hrank   = ws32 + IDX_HRANK(n);

    const size_t zero_bytes = (size_t)(16 + 2 * WORDS + n) * 4;  // scalars+masks+counts
    hipMemsetAsync(d_ws, 0, zero_bytes, stream);

    int nb = (n + 255) / 256;
    k_init      <<<nb, 256, 0, stream>>>(x, scalars, n);
    k_bits      <<<nb, 256, 0, stream>>>(x, t, scalars, mask1, mask2, n);
    k_scan1     <<<NB_SCAN, 256, 0, stream>>>(mask1, part);
    k_scan2     <<<1, 512, 0, stream>>>(part, part2, scalars);
    k_scan3     <<<NB_SCAN, 256, 0, stream>>>(mask1, part2, wbase);
    k_zero_multi<<<(WORDS + 255) / 256, 256, 0, stream>>>(mask1, mask2, wbase, out);
    k_scatter   <<<nb, 256, 0, stream>>>(x, t, u, user_emb, scalars, mask1, mask2,
                                         wbase, counts, hrank, out, n);
    k_gemm      <<<3125, 256, 0, stream>>>(loc_emb, time_emb, user_emb, W, bias,
                                           scalars, counts, hrank, out, n);
}